// Round 1
// baseline (3520.063 us; speedup 1.0000x reference)
//
#include <hip/hip_runtime.h>

// ---------------------------------------------------------------------------
// Birdsong LFADS forward. Dims (from reference):
//   B=32, T=512, D=4096, HE=HC=HG=64, FD=32, LD=16, UD=8
// Input indices (setup_inputs order):
//  0 x, 1 eps_g0, 2 eps_u,
//  3..6 g0f_{Wih,Whh,bih,bhh}, 7..10 g0b_*, 11..14 cef_*, 15..18 ceb_*,
//  19..22 ctrl_*, 23..26 genf_*, 27..30 genb_*,
//  31 g0lin_W, 32 g0lin_b, 33 ulin_W, 34 ulin_b,
//  35 l2gf_W, 36 l2gf_b, 37 l2gb_W, 38 l2gb_b, 39 fac_W, 40 fac_b,
//  41 rate_W, 42 rate_b
// Output (flat, fp32): logits(B,T,4096), f_t(B,T,32), mu_g0(32,16),
//  logvar_g0(32,16), mu_u(B,T,8), logvar_u(B,T,8)
// ---------------------------------------------------------------------------

#define TT 512
#define MALL 16384   // B*T

// d_out offsets (floats)
#define OFS_FT   67108864
#define OFS_MUG0 67633152
#define OFS_LVG0 67633664
#define OFS_MUU  67634176
#define OFS_LVU  67765248

__device__ __forceinline__ float sigm(float x) { return 1.0f / (1.0f + __expf(-x)); }
__device__ __forceinline__ float tanh_fast(float x) {
  float e = __expf(2.0f * x);
  return 1.0f - 2.0f / (e + 1.0f);
}

// ---------------------------------------------------------------------------
// K0: pack 4 encoder Wih into Wcat (768x4096), bih into bcat(768),
//     gen Wih into Wg(384x8), gen bih into bg(384)
// ---------------------------------------------------------------------------
__global__ void pack_kernel(const float* __restrict__ w0, const float* __restrict__ w1,
                            const float* __restrict__ w2, const float* __restrict__ w3,
                            const float* __restrict__ b0, const float* __restrict__ b1,
                            const float* __restrict__ b2, const float* __restrict__ b3,
                            const float* __restrict__ gwf, const float* __restrict__ gwb,
                            const float* __restrict__ gbf, const float* __restrict__ gbb,
                            float* __restrict__ Wcat, float* __restrict__ bcat,
                            float* __restrict__ Wg, float* __restrict__ bg) {
  int i = blockIdx.x * 256 + threadIdx.x;
  const int WSZ = 192 * 4096;
  if (i < 4 * WSZ) {
    int w = i / WSZ, r = i - w * WSZ;
    const float* s = (w == 0) ? w0 : (w == 1) ? w1 : (w == 2) ? w2 : w3;
    Wcat[i] = s[r];
    return;
  }
  i -= 4 * WSZ;
  if (i < 768) {
    int w = i / 192, r = i - w * 192;
    const float* s = (w == 0) ? b0 : (w == 1) ? b1 : (w == 2) ? b2 : b3;
    bcat[i] = s[r];
    return;
  }
  i -= 768;
  if (i < 384 * 8) { Wg[i] = (i < 192 * 8) ? gwf[i] : gwb[i - 1536]; return; }
  i -= 3072;
  if (i < 384) { bg[i] = (i < 192) ? gbf[i] : gbb[i - 192]; return; }
}

// ---------------------------------------------------------------------------
// Generic NT SGEMM: C[m][n] = sum_k A[m*lda+k]*B[n*ldb+k] + bias[n]
// BM=BN=64, BK=32, 256 threads, 4x4 microtile. M%64==0, N%64==0, K%32==0.
// ---------------------------------------------------------------------------
__global__ __launch_bounds__(256) void sgemm_nt(const float* __restrict__ A,
                                                const float* __restrict__ B,
                                                const float* __restrict__ bias,
                                                float* __restrict__ C,
                                                int M, int N, int K,
                                                int lda, int ldb, int ldc) {
  __shared__ float As[32][68];
  __shared__ float Bs[32][68];
  const int tid = threadIdx.x;
  const int tx = tid & 15, ty = tid >> 4;
  const int bm = blockIdx.y * 64, bn = blockIdx.x * 64;
  float acc[4][4] = {};
  for (int kt = 0; kt < K; kt += 32) {
    #pragma unroll
    for (int s = 0; s < 2; ++s) {
      int slot = tid + s * 256;
      int m = slot >> 3;
      int k4 = (slot & 7) << 2;
      float4 va = *(const float4*)(A + (size_t)(bm + m) * lda + kt + k4);
      As[k4 + 0][m] = va.x; As[k4 + 1][m] = va.y; As[k4 + 2][m] = va.z; As[k4 + 3][m] = va.w;
      float4 vb = *(const float4*)(B + (size_t)(bn + m) * ldb + kt + k4);
      Bs[k4 + 0][m] = vb.x; Bs[k4 + 1][m] = vb.y; Bs[k4 + 2][m] = vb.z; Bs[k4 + 3][m] = vb.w;
    }
    __syncthreads();
    #pragma unroll
    for (int kk = 0; kk < 32; ++kk) {
      float4 a4 = *(const float4*)&As[kk][ty << 2];
      float4 b4 = *(const float4*)&Bs[kk][tx << 2];
      float av[4] = {a4.x, a4.y, a4.z, a4.w};
      float bv[4] = {b4.x, b4.y, b4.z, b4.w};
      #pragma unroll
      for (int i = 0; i < 4; ++i)
        #pragma unroll
        for (int jj = 0; jj < 4; ++jj)
          acc[i][jj] = fmaf(av[i], bv[jj], acc[i][jj]);
    }
    __syncthreads();
  }
  float4 bb = *(const float4*)(bias + bn + (tx << 2));
  #pragma unroll
  for (int i = 0; i < 4; ++i) {
    int m = bm + (ty << 2) + i;
    float4 o;
    o.x = acc[i][0] + bb.x; o.y = acc[i][1] + bb.y;
    o.z = acc[i][2] + bb.z; o.w = acc[i][3] + bb.w;
    *(float4*)(C + (size_t)m * ldc + bn + (tx << 2)) = o;
  }
}

// ---------------------------------------------------------------------------
// GRU helpers: one wave per (direction, batch). h lives per-lane; broadcast
// through LDS. Whh (192x64) in 192 VGPRs per lane.
// ---------------------------------------------------------------------------
__device__ __forceinline__ void load_whh(const float* __restrict__ Whh, int j,
                                         float* wr, float* wz, float* wn) {
  #pragma unroll
  for (int k = 0; k < 64; k += 4) {
    float4 a = *(const float4*)(Whh + j * 64 + k);
    wr[k] = a.x; wr[k + 1] = a.y; wr[k + 2] = a.z; wr[k + 3] = a.w;
    float4 b = *(const float4*)(Whh + (64 + j) * 64 + k);
    wz[k] = b.x; wz[k + 1] = b.y; wz[k + 2] = b.z; wz[k + 3] = b.w;
    float4 c = *(const float4*)(Whh + (128 + j) * 64 + k);
    wn[k] = c.x; wn[k + 1] = c.y; wn[k + 2] = c.z; wn[k + 3] = c.w;
  }
}

__device__ __forceinline__ float gru_step(const float* wr, const float* wz, const float* wn,
                                          float br, float bz, float bn,
                                          const float* hs, float h,
                                          float ir, float iz, float inn) {
  float gr = 0.f, gz = 0.f, gn = 0.f;
  #pragma unroll
  for (int kk = 0; kk < 16; ++kk) {
    float4 h4 = ((const float4*)hs)[kk];
    gr = fmaf(wr[4 * kk + 0], h4.x, gr);
    gr = fmaf(wr[4 * kk + 1], h4.y, gr);
    gr = fmaf(wr[4 * kk + 2], h4.z, gr);
    gr = fmaf(wr[4 * kk + 3], h4.w, gr);
    gz = fmaf(wz[4 * kk + 0], h4.x, gz);
    gz = fmaf(wz[4 * kk + 1], h4.y, gz);
    gz = fmaf(wz[4 * kk + 2], h4.z, gz);
    gz = fmaf(wz[4 * kk + 3], h4.w, gz);
    gn = fmaf(wn[4 * kk + 0], h4.x, gn);
    gn = fmaf(wn[4 * kk + 1], h4.y, gn);
    gn = fmaf(wn[4 * kk + 2], h4.z, gn);
    gn = fmaf(wn[4 * kk + 3], h4.w, gn);
  }
  float r = sigm(ir + gr + br);
  float z = sigm(iz + gz + bz);
  float n = tanh_fast(inn + r * (gn + bn));
  return (1.f - z) * n + z * h;
}

// K2: 4 encoder GRUs (g0f, g0b fwd/bwd -> final hidden; cef, ceb -> full ys)
__global__ __launch_bounds__(64, 1) void enc_gru(const float* __restrict__ XP,
    const float* __restrict__ Whh0, const float* __restrict__ Whh1,
    const float* __restrict__ Whh2, const float* __restrict__ Whh3,
    const float* __restrict__ bhh0, const float* __restrict__ bhh1,
    const float* __restrict__ bhh2, const float* __restrict__ bhh3,
    float* __restrict__ hTbuf, float* __restrict__ enc_out) {
  const int gid = blockIdx.x >> 5;  // 0=g0f 1=g0b 2=cef 3=ceb
  const int b = blockIdx.x & 31;
  const int j = threadIdx.x;
  const float* Whh = (gid == 0) ? Whh0 : (gid == 1) ? Whh1 : (gid == 2) ? Whh2 : Whh3;
  const float* bhh = (gid == 0) ? bhh0 : (gid == 1) ? bhh1 : (gid == 2) ? bhh2 : bhh3;
  const bool bwd = (gid & 1);
  float wr[64], wz[64], wn[64];
  load_whh(Whh, j, wr, wz, wn);
  const float br = bhh[j], bz = bhh[64 + j], bn = bhh[128 + j];
  __shared__ __align__(16) float hs[64];
  float h = 0.f;
  hs[j] = h;
  __syncthreads();
  const int xofs = gid * 192;
  int time = bwd ? (TT - 1) : 0;
  const float* xr = XP + (size_t)(b * TT + time) * 768 + xofs;
  float ir = xr[j], iz = xr[64 + j], inn = xr[128 + j];
  for (int t = 0; t < TT; ++t) {
    float irn = 0.f, izn = 0.f, innn = 0.f;
    if (t < TT - 1) {
      int tn = bwd ? (TT - 2 - t) : (t + 1);
      const float* xn = XP + (size_t)(b * TT + tn) * 768 + xofs;
      irn = xn[j]; izn = xn[64 + j]; innn = xn[128 + j];
    }
    h = gru_step(wr, wz, wn, br, bz, bn, hs, h, ir, iz, inn);
    if (gid >= 2) enc_out[(size_t)(b * TT + time) * 128 + (gid - 2) * 64 + j] = h;
    __syncthreads();
    hs[j] = h;
    __syncthreads();
    ir = irn; iz = izn; inn = innn;
    time = bwd ? (time - 1) : (time + 1);
  }
  if (gid < 2) hTbuf[gid * 2048 + b * 64 + j] = h;
}

// K4/K10: generator bidir GRU. xp==nullptr -> pass 1 (u=0, input proj = bih).
__global__ __launch_bounds__(64, 1) void gen_gru(const float* __restrict__ xp,
    const float* __restrict__ bg,
    const float* __restrict__ WhhF, const float* __restrict__ WhhB,
    const float* __restrict__ bhhF, const float* __restrict__ bhhB,
    const float* __restrict__ h0buf, float* __restrict__ genout) {
  const int gid = blockIdx.x >> 5;  // 0=genf 1=genb
  const int b = blockIdx.x & 31;
  const int j = threadIdx.x;
  const float* Whh = gid ? WhhB : WhhF;
  const float* bhh = gid ? bhhB : bhhF;
  const bool bwd = gid;
  float wr[64], wz[64], wn[64];
  load_whh(Whh, j, wr, wz, wn);
  const float br = bhh[j], bz = bhh[64 + j], bn = bhh[128 + j];
  __shared__ __align__(16) float hs[64];
  float h = h0buf[gid * 2048 + b * 64 + j];
  hs[j] = h;
  __syncthreads();
  const float cir = bg[gid * 192 + j], ciz = bg[gid * 192 + 64 + j], cin = bg[gid * 192 + 128 + j];
  const int xofs = gid * 192;
  int time = bwd ? (TT - 1) : 0;
  float ir = cir, iz = ciz, inn = cin;
  if (xp) {
    const float* xr = xp + (size_t)(b * TT + time) * 384 + xofs;
    ir = xr[j]; iz = xr[64 + j]; inn = xr[128 + j];
  }
  for (int t = 0; t < TT; ++t) {
    float irn = cir, izn = ciz, innn = cin;
    if (xp && t < TT - 1) {
      int tn = bwd ? (TT - 2 - t) : (t + 1);
      const float* xn = xp + (size_t)(b * TT + tn) * 384 + xofs;
      irn = xn[j]; izn = xn[64 + j]; innn = xn[128 + j];
    }
    h = gru_step(wr, wz, wn, br, bz, bn, hs, h, ir, iz, inn);
    genout[(size_t)(b * TT + time) * 128 + gid * 64 + j] = h;
    __syncthreads();
    hs[j] = h;
    __syncthreads();
    ir = irn; iz = izn; inn = innn;
    time = bwd ? (time - 1) : (time + 1);
  }
}

// K7: controller forward GRU -> full ys
__global__ __launch_bounds__(64, 1) void ctrl_gru(const float* __restrict__ xp,
    const float* __restrict__ Whh, const float* __restrict__ bhh,
    float* __restrict__ ys) {
  const int b = blockIdx.x;
  const int j = threadIdx.x;
  float wr[64], wz[64], wn[64];
  load_whh(Whh, j, wr, wz, wn);
  const float br = bhh[j], bz = bhh[64 + j], bn = bhh[128 + j];
  __shared__ __align__(16) float hs[64];
  float h = 0.f;
  hs[j] = h;
  __syncthreads();
  const float* xr = xp + (size_t)(b * TT) * 192;
  float ir = xr[j], iz = xr[64 + j], inn = xr[128 + j];
  for (int t = 0; t < TT; ++t) {
    float irn = 0.f, izn = 0.f, innn = 0.f;
    if (t < TT - 1) {
      const float* xn = xp + (size_t)(b * TT + t + 1) * 192;
      irn = xn[j]; izn = xn[64 + j]; innn = xn[128 + j];
    }
    h = gru_step(wr, wz, wn, br, bz, bn, hs, h, ir, iz, inn);
    ys[(size_t)(b * TT + t) * 64 + j] = h;
    __syncthreads();
    hs[j] = h;
    __syncthreads();
    ir = irn; iz = izn; inn = innn;
  }
}

// K3: g0 linear + reparam + generator h0 projections. One block, 1024 thr.
__global__ __launch_bounds__(1024) void g0_kernel(const float* __restrict__ hTbuf,
    const float* __restrict__ g0lin_W, const float* __restrict__ g0lin_b,
    const float* __restrict__ eps_g0,
    const float* __restrict__ l2gf_W, const float* __restrict__ l2gf_b,
    const float* __restrict__ l2gb_W, const float* __restrict__ l2gb_b,
    float* __restrict__ mu_g0, float* __restrict__ logvar_g0,
    float* __restrict__ h0buf) {
  __shared__ float up[32 * 32];
  __shared__ float g0s[32 * 16];
  const int tid = threadIdx.x;
  const int b = tid >> 5, c = tid & 31;
  float acc = g0lin_b[c];
  for (int k = 0; k < 128; ++k) {
    float hv = (k < 64) ? hTbuf[b * 64 + k] : hTbuf[2048 + b * 64 + (k - 64)];
    acc = fmaf(hv, g0lin_W[c * 128 + k], acc);
  }
  up[b * 32 + c] = acc;
  __syncthreads();
  if (c < 16) {
    float mu = up[b * 32 + c], lv = up[b * 32 + 16 + c];
    mu_g0[b * 16 + c] = mu;
    logvar_g0[b * 16 + c] = lv;
    g0s[b * 16 + c] = mu + eps_g0[b * 16 + c] * __expf(0.5f * lv);
  }
  __syncthreads();
  #pragma unroll
  for (int rep = 0; rep < 4; ++rep) {
    int idx = rep * 1024 + tid;
    int bb = idx >> 7, jj = idx & 127;
    int dir = jj >> 6, j = jj & 63;
    const float* W = dir ? l2gb_W : l2gf_W;
    const float* bias = dir ? l2gb_b : l2gf_b;
    float a = bias[j];
    #pragma unroll
    for (int i = 0; i < 8; ++i) a = fmaf(g0s[bb * 16 + dir * 8 + i], W[j * 8 + i], a);
    h0buf[dir * 2048 + bb * 64 + j] = a;
  }
}

// K5/K11: f = gen_out(.,128) @ fac_W^T(32x128) + fac_b. 4 rows per block.
__global__ __launch_bounds__(128) void f_kernel(const float* __restrict__ gen_out,
    const float* __restrict__ fac_W, const float* __restrict__ fac_b,
    float* __restrict__ f) {
  __shared__ float gl[4 * 130];
  __shared__ float fw[32 * 130];
  const int tid = threadIdx.x;
  const int row0 = blockIdx.x * 4;
  #pragma unroll
  for (int s = 0; s < 4; ++s) {
    int idx = s * 128 + tid;
    gl[(idx >> 7) * 130 + (idx & 127)] = gen_out[(size_t)row0 * 128 + idx];
  }
  for (int s = 0; s < 32; ++s) {
    int idx = s * 128 + tid;
    fw[(idx >> 7) * 130 + (idx & 127)] = fac_W[idx];
  }
  __syncthreads();
  const int r = tid >> 5, c = tid & 31;
  float acc = fac_b[c];
  #pragma unroll 8
  for (int k = 0; k < 128; ++k) acc = fmaf(gl[r * 130 + k], fw[c * 130 + k], acc);
  f[(size_t)(row0 + r) * 32 + c] = acc;
}

// K5b: ctrl_in = [enc_out | f_shift]
__global__ void build_ctrl_in(const float* __restrict__ enc_out,
                              const float* __restrict__ f_init,
                              float* __restrict__ ctrl_in) {
  int idx = blockIdx.x * 256 + threadIdx.x;
  if (idx >= MALL * 160) return;
  int row = idx / 160, i = idx - row * 160;
  float v;
  if (i < 128) v = enc_out[(size_t)row * 128 + i];
  else {
    int t = row & (TT - 1);
    v = (t == 0) ? 0.f : f_init[(size_t)(row - 1) * 32 + (i - 128)];
  }
  ctrl_in[idx] = v;
}

// K8: up = ctrl_ys @ ulin^T + b; split mu/logvar; sample u. 16 rows/block.
__global__ __launch_bounds__(256) void ctrl_out_kernel(const float* __restrict__ ys,
    const float* __restrict__ ulin_W, const float* __restrict__ ulin_b,
    const float* __restrict__ eps_u,
    float* __restrict__ mu_u, float* __restrict__ logvar_u, float* __restrict__ u) {
  __shared__ float ysl[16 * 66];
  __shared__ float wl[16 * 66];
  __shared__ float upl[16 * 16];
  const int tid = threadIdx.x;
  const int row0 = blockIdx.x * 16;
  #pragma unroll
  for (int s = 0; s < 4; ++s) {
    int idx = s * 256 + tid;
    ysl[(idx >> 6) * 66 + (idx & 63)] = ys[(size_t)row0 * 64 + idx];
    wl[(idx >> 6) * 66 + (idx & 63)] = ulin_W[idx];
  }
  __syncthreads();
  const int r = tid >> 4, c = tid & 15;
  float acc = ulin_b[c];
  #pragma unroll 8
  for (int k = 0; k < 64; ++k) acc = fmaf(ysl[r * 66 + k], wl[c * 66 + k], acc);
  upl[r * 16 + c] = acc;
  __syncthreads();
  if (c < 8) {
    int row = row0 + r;
    float mu = upl[r * 16 + c], lv = upl[r * 16 + c + 8];
    mu_u[(size_t)row * 8 + c] = mu;
    logvar_u[(size_t)row * 8 + c] = lv;
    u[(size_t)row * 8 + c] = mu + eps_u[(size_t)row * 8 + c] * __expf(0.5f * lv);
  }
}

// K9: xp_gen2 = u(.,8) @ Wg^T(384x8) + bg. One row per block, 384 threads.
__global__ __launch_bounds__(384) void gen_xp2(const float* __restrict__ u,
    const float* __restrict__ Wg, const float* __restrict__ bg,
    float* __restrict__ xp) {
  __shared__ float us[8];
  const int row = blockIdx.x, o = threadIdx.x;
  if (o < 8) us[o] = u[(size_t)row * 8 + o];
  __syncthreads();
  float4 w0 = *(const float4*)(Wg + o * 8);
  float4 w1 = *(const float4*)(Wg + o * 8 + 4);
  float acc = bg[o];
  acc = fmaf(w0.x, us[0], acc); acc = fmaf(w0.y, us[1], acc);
  acc = fmaf(w0.z, us[2], acc); acc = fmaf(w0.w, us[3], acc);
  acc = fmaf(w1.x, us[4], acc); acc = fmaf(w1.y, us[5], acc);
  acc = fmaf(w1.z, us[6], acc); acc = fmaf(w1.w, us[7], acc);
  xp[(size_t)row * 384 + o] = acc;
}

// K12: logits = f(.,32) @ rate_W^T(4096x32) + rate_b. 16 rows x 256 cols/blk.
__global__ __launch_bounds__(256) void logits_kernel(const float* __restrict__ Fm,
    const float* __restrict__ rate_W, const float* __restrict__ rate_b,
    float* __restrict__ out) {
  __shared__ __align__(16) float fs[16 * 32];
  const int tid = threadIdx.x;
  const int m0 = blockIdx.y * 16;
  const int col = blockIdx.x * 256 + tid;
  ((float2*)fs)[tid] = ((const float2*)(Fm + (size_t)m0 * 32))[tid];
  __syncthreads();
  float w[32];
  #pragma unroll
  for (int k4 = 0; k4 < 8; ++k4) {
    float4 v = *(const float4*)(rate_W + (size_t)col * 32 + k4 * 4);
    w[k4 * 4 + 0] = v.x; w[k4 * 4 + 1] = v.y; w[k4 * 4 + 2] = v.z; w[k4 * 4 + 3] = v.w;
  }
  const float rb = rate_b[col];
  #pragma unroll
  for (int r = 0; r < 16; ++r) {
    float acc = rb;
    #pragma unroll
    for (int k4 = 0; k4 < 8; ++k4) {
      float4 f4 = ((const float4*)fs)[r * 8 + k4];
      acc = fmaf(f4.x, w[k4 * 4 + 0], acc);
      acc = fmaf(f4.y, w[k4 * 4 + 1], acc);
      acc = fmaf(f4.z, w[k4 * 4 + 2], acc);
      acc = fmaf(f4.w, w[k4 * 4 + 3], acc);
    }
    out[(size_t)(m0 + r) * 4096 + col] = acc;
  }
}

// ---------------------------------------------------------------------------
extern "C" void kernel_launch(void* const* d_in, const int* in_sizes, int n_in,
                              void* d_out, int out_size, void* d_ws, size_t ws_size,
                              hipStream_t stream) {
  const float* x        = (const float*)d_in[0];
  const float* eps_g0   = (const float*)d_in[1];
  const float* eps_u    = (const float*)d_in[2];
  const float* g0f_Wih  = (const float*)d_in[3];
  const float* g0f_Whh  = (const float*)d_in[4];
  const float* g0f_bih  = (const float*)d_in[5];
  const float* g0f_bhh  = (const float*)d_in[6];
  const float* g0b_Wih  = (const float*)d_in[7];
  const float* g0b_Whh  = (const float*)d_in[8];
  const float* g0b_bih  = (const float*)d_in[9];
  const float* g0b_bhh  = (const float*)d_in[10];
  const float* cef_Wih  = (const float*)d_in[11];
  const float* cef_Whh  = (const float*)d_in[12];
  const float* cef_bih  = (const float*)d_in[13];
  const float* cef_bhh  = (const float*)d_in[14];
  const float* ceb_Wih  = (const float*)d_in[15];
  const float* ceb_Whh  = (const float*)d_in[16];
  const float* ceb_bih  = (const float*)d_in[17];
  const float* ceb_bhh  = (const float*)d_in[18];
  const float* ctrl_Wih = (const float*)d_in[19];
  const float* ctrl_Whh = (const float*)d_in[20];
  const float* ctrl_bih = (const float*)d_in[21];
  const float* ctrl_bhh = (const float*)d_in[22];
  const float* genf_Wih = (const float*)d_in[23];
  const float* genf_Whh = (const float*)d_in[24];
  const float* genf_bih = (const float*)d_in[25];
  const float* genf_bhh = (const float*)d_in[26];
  const float* genb_Wih = (const float*)d_in[27];
  const float* genb_Whh = (const float*)d_in[28];
  const float* genb_bih = (const float*)d_in[29];
  const float* genb_bhh = (const float*)d_in[30];
  const float* g0lin_W  = (const float*)d_in[31];
  const float* g0lin_b  = (const float*)d_in[32];
  const float* ulin_W   = (const float*)d_in[33];
  const float* ulin_b   = (const float*)d_in[34];
  const float* l2gf_W   = (const float*)d_in[35];
  const float* l2gf_b   = (const float*)d_in[36];
  const float* l2gb_W   = (const float*)d_in[37];
  const float* l2gb_b   = (const float*)d_in[38];
  const float* fac_W    = (const float*)d_in[39];
  const float* fac_b    = (const float*)d_in[40];
  const float* rate_W   = (const float*)d_in[41];
  const float* rate_b   = (const float*)d_in[42];

  float* ws = (float*)d_ws;
  // workspace layout (floats); XP region (12.58M) is overlaid by
  // ctrl_in / xp_ctrl / xp_gen2 after the encoder recurrence consumes XP.
  float* Wcat    = ws;                       // 3,145,728
  float* XP      = Wcat + 3145728;           // 12,582,912
  float* ctrl_in = XP;                       // 2,621,440 (overlay)
  float* xp_ctrl = XP + 2621440;             // 3,145,728 (overlay)
  float* xp_gen2 = XP + 5767168;             // 6,291,456 (overlay)
  float* bcat    = XP + 12582912;            // 768
  float* Wg      = bcat + 768;               // 3,072
  float* bg      = Wg + 3072;                // 384
  float* hTbuf   = bg + 384;                 // 4,096
  float* h0buf   = hTbuf + 4096;             // 4,096
  float* enc_out = h0buf + 4096;             // 2,097,152
  float* genout  = enc_out + 2097152;        // 2,097,152
  float* f_init  = genout + 2097152;         // 524,288
  float* ctrl_ys = f_init + 524288;          // 1,048,576
  float* u_buf   = ctrl_ys + 1048576;        // 131,072  (total ~86.6 MB)

  float* out  = (float*)d_out;
  float* f_t  = out + OFS_FT;

  // K0: pack concatenated weights
  pack_kernel<<<12305, 256, 0, stream>>>(g0f_Wih, g0b_Wih, cef_Wih, ceb_Wih,
                                         g0f_bih, g0b_bih, cef_bih, ceb_bih,
                                         genf_Wih, genb_Wih, genf_bih, genb_bih,
                                         Wcat, bcat, Wg, bg);
  // K1: big fused encoder input projection  (16384x768, K=4096)
  sgemm_nt<<<dim3(12, 256), 256, 0, stream>>>(x, Wcat, bcat, XP,
                                              MALL, 768, 4096, 4096, 4096, 768);
  // K2: 4 encoder GRU recurrences
  enc_gru<<<128, 64, 0, stream>>>(XP, g0f_Whh, g0b_Whh, cef_Whh, ceb_Whh,
                                  g0f_bhh, g0b_bhh, cef_bhh, ceb_bhh,
                                  hTbuf, enc_out);
  // K3: g0 linear + reparam + generator h0
  g0_kernel<<<1, 1024, 0, stream>>>(hTbuf, g0lin_W, g0lin_b, eps_g0,
                                    l2gf_W, l2gf_b, l2gb_W, l2gb_b,
                                    out + OFS_MUG0, out + OFS_LVG0, h0buf);
  // K4: generator pass 1 (u = 0 -> input proj = bih only)
  gen_gru<<<64, 64, 0, stream>>>(nullptr, bg, genf_Whh, genb_Whh,
                                 genf_bhh, genb_bhh, h0buf, genout);
  // K5: f_init
  f_kernel<<<4096, 128, 0, stream>>>(genout, fac_W, fac_b, f_init);
  // K5b: controller input concat
  build_ctrl_in<<<10240, 256, 0, stream>>>(enc_out, f_init, ctrl_in);
  // K6: controller input projection (16384x192, K=160)
  sgemm_nt<<<dim3(3, 256), 256, 0, stream>>>(ctrl_in, ctrl_Wih, ctrl_bih, xp_ctrl,
                                             MALL, 192, 160, 160, 160, 192);
  // K7: controller GRU
  ctrl_gru<<<32, 64, 0, stream>>>(xp_ctrl, ctrl_Whh, ctrl_bhh, ctrl_ys);
  // K8: u-posterior linear + reparam
  ctrl_out_kernel<<<1024, 256, 0, stream>>>(ctrl_ys, ulin_W, ulin_b, eps_u,
                                            out + OFS_MUU, out + OFS_LVU, u_buf);
  // K9: generator pass-2 input projection
  gen_xp2<<<16384, 384, 0, stream>>>(u_buf, Wg, bg, xp_gen2);
  // K10: generator pass 2
  gen_gru<<<64, 64, 0, stream>>>(xp_gen2, bg, genf_Whh, genb_Whh,
                                 genf_bhh, genb_bhh, h0buf, genout);
  // K11: f_t (written straight to d_out; also read by K12)
  f_kernel<<<4096, 128, 0, stream>>>(genout, fac_W, fac_b, f_t);
  // K12: logits
  logits_kernel<<<dim3(16, 1024), 256, 0, stream>>>(f_t, rate_W, rate_b, out);
}

// Round 2
// 2508.862 us; speedup vs baseline: 1.4031x; 1.4031x over previous
//
#include <hip/hip_runtime.h>

// ---------------------------------------------------------------------------
// Birdsong LFADS forward. Dims: B=32, T=512, D=4096, HE=HC=HG=64, FD=32,
// LD=16, UD=8.  Output (flat, fp32): logits(B,T,4096), f_t(B,T,32),
// mu_g0(32,16), logvar_g0(32,16), mu_u(B,T,8), logvar_u(B,T,8)
// ---------------------------------------------------------------------------

#define TT 512
#define MALL 16384   // B*T
#define GK 4096
#define GN 768

// d_out offsets (floats)
#define OFS_FT   67108864
#define OFS_MUG0 67633152
#define OFS_LVG0 67633664
#define OFS_MUU  67634176
#define OFS_LVU  67765248

typedef __bf16 v8bf __attribute__((ext_vector_type(8)));
typedef float  v4f  __attribute__((ext_vector_type(4)));

__device__ __forceinline__ float sigm(float x) { return 1.0f / (1.0f + __expf(-x)); }
__device__ __forceinline__ float tanh_fast(float x) {
  float e = __expf(2.0f * x);
  return 1.0f - 2.0f / (e + 1.0f);
}

// ---------------------------------------------------------------------------
// K-1: split-convert x (fp32) -> xh + xl (bf16 pair). 8 elems/thread.
// ---------------------------------------------------------------------------
__global__ __launch_bounds__(256) void cvt_split(const float* __restrict__ x,
                                                 __bf16* __restrict__ xh,
                                                 __bf16* __restrict__ xl) {
  size_t i = ((size_t)blockIdx.x * 256 + threadIdx.x) * 8;
  float4 a = *(const float4*)(x + i);
  float4 b = *(const float4*)(x + i + 4);
  float v[8] = {a.x, a.y, a.z, a.w, b.x, b.y, b.z, b.w};
  v8bf h, l;
  #pragma unroll
  for (int j = 0; j < 8; ++j) {
    __bf16 hi = (__bf16)v[j];
    h[j] = hi;
    l[j] = (__bf16)(v[j] - (float)hi);
  }
  *(v8bf*)(xh + i) = h;
  *(v8bf*)(xl + i) = l;
}

// ---------------------------------------------------------------------------
// K0: pack 4 encoder Wih into Wh/Wl (768x4096 bf16 pair), bih into bcat(768),
//     gen Wih into Wg(384x8), gen bih into bg(384)
// ---------------------------------------------------------------------------
__global__ void pack_kernel(const float* __restrict__ w0, const float* __restrict__ w1,
                            const float* __restrict__ w2, const float* __restrict__ w3,
                            const float* __restrict__ b0, const float* __restrict__ b1,
                            const float* __restrict__ b2, const float* __restrict__ b3,
                            const float* __restrict__ gwf, const float* __restrict__ gwb,
                            const float* __restrict__ gbf, const float* __restrict__ gbb,
                            __bf16* __restrict__ Wh, __bf16* __restrict__ Wl,
                            float* __restrict__ bcat,
                            float* __restrict__ Wg, float* __restrict__ bg) {
  int i = blockIdx.x * 256 + threadIdx.x;
  const int WSZ = 192 * 4096;
  if (i < 4 * WSZ) {
    int w = i / WSZ, r = i - w * WSZ;
    const float* s = (w == 0) ? w0 : (w == 1) ? w1 : (w == 2) ? w2 : w3;
    float v = s[r];
    __bf16 hi = (__bf16)v;
    Wh[i] = hi;
    Wl[i] = (__bf16)(v - (float)hi);
    return;
  }
  i -= 4 * WSZ;
  if (i < 768) {
    int w = i / 192, r = i - w * 192;
    const float* s = (w == 0) ? b0 : (w == 1) ? b1 : (w == 2) ? b2 : b3;
    bcat[i] = s[r];
    return;
  }
  i -= 768;
  if (i < 384 * 8) { Wg[i] = (i < 192 * 8) ? gwf[i] : gwb[i - 1536]; return; }
  i -= 3072;
  if (i < 384) { bg[i] = (i < 192) ? gbf[i] : gbb[i - 192]; return; }
}

// ---------------------------------------------------------------------------
// K1: XP(16384x768) = [xh+xl](16384x4096) @ [Wh+Wl]^T + bcat  via 3-term
// split bf16 MFMA (xh*Wh + xl*Wh + xh*Wl). 128x128 tile, BK=32, 4 waves,
// 16x16x32 MFMA, K-padded LDS (40 bf16 stride) to kill frag bank conflicts.
// ---------------------------------------------------------------------------
__global__ __launch_bounds__(256) void gemm_bf16split(
    const __bf16* __restrict__ Xh, const __bf16* __restrict__ Xl,
    const __bf16* __restrict__ Wh, const __bf16* __restrict__ Wl,
    const float* __restrict__ bias, float* __restrict__ C) {
  __shared__ __bf16 Ah[128][40];
  __shared__ __bf16 Al[128][40];
  __shared__ __bf16 Bh[128][40];
  __shared__ __bf16 Bl[128][40];
  const int tid = threadIdx.x;
  const int lane = tid & 63;
  const int wave = tid >> 6;
  const int wrow = (wave >> 1) * 64, wcol = (wave & 1) * 64;
  const int bm = blockIdx.y * 128;
  const int bn = blockIdx.x * 128;
  const int ar = tid >> 2;        // staging row 0..63 (+64 on 2nd pass)
  const int ak = (tid & 3) * 8;   // staging k offset {0,8,16,24}
  const int lr = lane & 15, quad = lane >> 4;
  v4f acc[4][4];
  #pragma unroll
  for (int i = 0; i < 4; ++i)
    #pragma unroll
    for (int j = 0; j < 4; ++j) acc[i][j] = (v4f)(0.f);

  for (int kt = 0; kt < GK; kt += 32) {
    #pragma unroll
    for (int s = 0; s < 2; ++s) {
      int row = ar + s * 64;
      v8bf vah = *(const v8bf*)(Xh + (size_t)(bm + row) * GK + kt + ak);
      v8bf val = *(const v8bf*)(Xl + (size_t)(bm + row) * GK + kt + ak);
      v8bf vbh = *(const v8bf*)(Wh + (size_t)(bn + row) * GK + kt + ak);
      v8bf vbl = *(const v8bf*)(Wl + (size_t)(bn + row) * GK + kt + ak);
      *(v8bf*)&Ah[row][ak] = vah;
      *(v8bf*)&Al[row][ak] = val;
      *(v8bf*)&Bh[row][ak] = vbh;
      *(v8bf*)&Bl[row][ak] = vbl;
    }
    __syncthreads();
    v8bf fah[4], fal[4], fbh[4], fbl[4];
    #pragma unroll
    for (int i = 0; i < 4; ++i) {
      fah[i] = *(const v8bf*)&Ah[wrow + i * 16 + lr][quad * 8];
      fal[i] = *(const v8bf*)&Al[wrow + i * 16 + lr][quad * 8];
      fbh[i] = *(const v8bf*)&Bh[wcol + i * 16 + lr][quad * 8];
      fbl[i] = *(const v8bf*)&Bl[wcol + i * 16 + lr][quad * 8];
    }
    #pragma unroll
    for (int i = 0; i < 4; ++i)
      #pragma unroll
      for (int j = 0; j < 4; ++j) {
        acc[i][j] = __builtin_amdgcn_mfma_f32_16x16x32_bf16(fah[i], fbh[j], acc[i][j], 0, 0, 0);
        acc[i][j] = __builtin_amdgcn_mfma_f32_16x16x32_bf16(fal[i], fbh[j], acc[i][j], 0, 0, 0);
        acc[i][j] = __builtin_amdgcn_mfma_f32_16x16x32_bf16(fah[i], fbl[j], acc[i][j], 0, 0, 0);
      }
    __syncthreads();
  }
  // epilogue: C/D layout col=lane&15, row=quad*4+reg
  #pragma unroll
  for (int j = 0; j < 4; ++j) {
    int col = bn + wcol + j * 16 + lr;
    float bb = bias[col];
    #pragma unroll
    for (int i = 0; i < 4; ++i) {
      #pragma unroll
      for (int r = 0; r < 4; ++r) {
        int row = bm + wrow + i * 16 + quad * 4 + r;
        C[(size_t)row * GN + col] = acc[i][j][r] + bb;
      }
    }
  }
}

// ---------------------------------------------------------------------------
// Generic NT SGEMM (kept for the small fp32 ctrl projection).
// ---------------------------------------------------------------------------
__global__ __launch_bounds__(256) void sgemm_nt(const float* __restrict__ A,
                                                const float* __restrict__ B,
                                                const float* __restrict__ bias,
                                                float* __restrict__ C,
                                                int M, int N, int K,
                                                int lda, int ldb, int ldc) {
  __shared__ float As[32][68];
  __shared__ float Bs[32][68];
  const int tid = threadIdx.x;
  const int tx = tid & 15, ty = tid >> 4;
  const int bm = blockIdx.y * 64, bn = blockIdx.x * 64;
  float acc[4][4] = {};
  for (int kt = 0; kt < K; kt += 32) {
    #pragma unroll
    for (int s = 0; s < 2; ++s) {
      int slot = tid + s * 256;
      int m = slot >> 3;
      int k4 = (slot & 7) << 2;
      float4 va = *(const float4*)(A + (size_t)(bm + m) * lda + kt + k4);
      As[k4 + 0][m] = va.x; As[k4 + 1][m] = va.y; As[k4 + 2][m] = va.z; As[k4 + 3][m] = va.w;
      float4 vb = *(const float4*)(B + (size_t)(bn + m) * ldb + kt + k4);
      Bs[k4 + 0][m] = vb.x; Bs[k4 + 1][m] = vb.y; Bs[k4 + 2][m] = vb.z; Bs[k4 + 3][m] = vb.w;
    }
    __syncthreads();
    #pragma unroll
    for (int kk = 0; kk < 32; ++kk) {
      float4 a4 = *(const float4*)&As[kk][ty << 2];
      float4 b4 = *(const float4*)&Bs[kk][tx << 2];
      float av[4] = {a4.x, a4.y, a4.z, a4.w};
      float bv[4] = {b4.x, b4.y, b4.z, b4.w};
      #pragma unroll
      for (int i = 0; i < 4; ++i)
        #pragma unroll
        for (int jj = 0; jj < 4; ++jj)
          acc[i][jj] = fmaf(av[i], bv[jj], acc[i][jj]);
    }
    __syncthreads();
  }
  float4 bb = *(const float4*)(bias + bn + (tx << 2));
  #pragma unroll
  for (int i = 0; i < 4; ++i) {
    int m = bm + (ty << 2) + i;
    float4 o;
    o.x = acc[i][0] + bb.x; o.y = acc[i][1] + bb.y;
    o.z = acc[i][2] + bb.z; o.w = acc[i][3] + bb.w;
    *(float4*)(C + (size_t)m * ldc + bn + (tx << 2)) = o;
  }
}

// ---------------------------------------------------------------------------
// GRU helpers: one wave per (direction, batch). h broadcast via LDS,
// double-buffered so each step needs ONE barrier.
// ---------------------------------------------------------------------------
__device__ __forceinline__ void load_whh(const float* __restrict__ Whh, int j,
                                         float* wr, float* wz, float* wn) {
  #pragma unroll
  for (int k = 0; k < 64; k += 4) {
    float4 a = *(const float4*)(Whh + j * 64 + k);
    wr[k] = a.x; wr[k + 1] = a.y; wr[k + 2] = a.z; wr[k + 3] = a.w;
    float4 b = *(const float4*)(Whh + (64 + j) * 64 + k);
    wz[k] = b.x; wz[k + 1] = b.y; wz[k + 2] = b.z; wz[k + 3] = b.w;
    float4 c = *(const float4*)(Whh + (128 + j) * 64 + k);
    wn[k] = c.x; wn[k + 1] = c.y; wn[k + 2] = c.z; wn[k + 3] = c.w;
  }
}

__device__ __forceinline__ float gru_step(const float* wr, const float* wz, const float* wn,
                                          float br, float bz, float bn,
                                          const float* hs, float h,
                                          float ir, float iz, float inn) {
  float gr = 0.f, gz = 0.f, gn = 0.f;
  #pragma unroll
  for (int kk = 0; kk < 16; ++kk) {
    float4 h4 = ((const float4*)hs)[kk];
    gr = fmaf(wr[4 * kk + 0], h4.x, gr);
    gr = fmaf(wr[4 * kk + 1], h4.y, gr);
    gr = fmaf(wr[4 * kk + 2], h4.z, gr);
    gr = fmaf(wr[4 * kk + 3], h4.w, gr);
    gz = fmaf(wz[4 * kk + 0], h4.x, gz);
    gz = fmaf(wz[4 * kk + 1], h4.y, gz);
    gz = fmaf(wz[4 * kk + 2], h4.z, gz);
    gz = fmaf(wz[4 * kk + 3], h4.w, gz);
    gn = fmaf(wn[4 * kk + 0], h4.x, gn);
    gn = fmaf(wn[4 * kk + 1], h4.y, gn);
    gn = fmaf(wn[4 * kk + 2], h4.z, gn);
    gn = fmaf(wn[4 * kk + 3], h4.w, gn);
  }
  float r = sigm(ir + gr + br);
  float z = sigm(iz + gz + bz);
  float n = tanh_fast(inn + r * (gn + bn));
  return (1.f - z) * n + z * h;
}

// K2: 4 encoder GRUs (g0f, g0b -> final hidden; cef, ceb -> full ys)
__global__ __launch_bounds__(64, 1) void enc_gru(const float* __restrict__ XP,
    const float* __restrict__ Whh0, const float* __restrict__ Whh1,
    const float* __restrict__ Whh2, const float* __restrict__ Whh3,
    const float* __restrict__ bhh0, const float* __restrict__ bhh1,
    const float* __restrict__ bhh2, const float* __restrict__ bhh3,
    float* __restrict__ hTbuf, float* __restrict__ enc_out) {
  const int gid = blockIdx.x >> 5;  // 0=g0f 1=g0b 2=cef 3=ceb
  const int b = blockIdx.x & 31;
  const int j = threadIdx.x;
  const float* Whh = (gid == 0) ? Whh0 : (gid == 1) ? Whh1 : (gid == 2) ? Whh2 : Whh3;
  const float* bhh = (gid == 0) ? bhh0 : (gid == 1) ? bhh1 : (gid == 2) ? bhh2 : bhh3;
  const bool bwd = (gid & 1);
  float wr[64], wz[64], wn[64];
  load_whh(Whh, j, wr, wz, wn);
  const float br = bhh[j], bz = bhh[64 + j], bn = bhh[128 + j];
  __shared__ __align__(16) float hs[2][64];
  float h = 0.f;
  int cur = 0;
  hs[0][j] = h;
  __syncthreads();
  const int xofs = gid * 192;
  int time = bwd ? (TT - 1) : 0;
  const float* xr = XP + (size_t)(b * TT + time) * 768 + xofs;
  float ir = xr[j], iz = xr[64 + j], inn = xr[128 + j];
  for (int t = 0; t < TT; ++t) {
    float irn = 0.f, izn = 0.f, innn = 0.f;
    if (t < TT - 1) {
      int tn = bwd ? (TT - 2 - t) : (t + 1);
      const float* xn = XP + (size_t)(b * TT + tn) * 768 + xofs;
      irn = xn[j]; izn = xn[64 + j]; innn = xn[128 + j];
    }
    h = gru_step(wr, wz, wn, br, bz, bn, hs[cur], h, ir, iz, inn);
    if (gid >= 2) enc_out[(size_t)(b * TT + time) * 128 + (gid - 2) * 64 + j] = h;
    hs[cur ^ 1][j] = h;
    __syncthreads();
    cur ^= 1;
    ir = irn; iz = izn; inn = innn;
    time = bwd ? (time - 1) : (time + 1);
  }
  if (gid < 2) hTbuf[gid * 2048 + b * 64 + j] = h;
}

// K4/K10: generator bidir GRU. xp==nullptr -> pass 1 (u=0, proj = bih).
__global__ __launch_bounds__(64, 1) void gen_gru(const float* __restrict__ xp,
    const float* __restrict__ bg,
    const float* __restrict__ WhhF, const float* __restrict__ WhhB,
    const float* __restrict__ bhhF, const float* __restrict__ bhhB,
    const float* __restrict__ h0buf, float* __restrict__ genout) {
  const int gid = blockIdx.x >> 5;  // 0=genf 1=genb
  const int b = blockIdx.x & 31;
  const int j = threadIdx.x;
  const float* Whh = gid ? WhhB : WhhF;
  const float* bhh = gid ? bhhB : bhhF;
  const bool bwd = gid;
  float wr[64], wz[64], wn[64];
  load_whh(Whh, j, wr, wz, wn);
  const float br = bhh[j], bz = bhh[64 + j], bn = bhh[128 + j];
  __shared__ __align__(16) float hs[2][64];
  float h = h0buf[gid * 2048 + b * 64 + j];
  int cur = 0;
  hs[0][j] = h;
  __syncthreads();
  const float cir = bg[gid * 192 + j], ciz = bg[gid * 192 + 64 + j], cin = bg[gid * 192 + 128 + j];
  const int xofs = gid * 192;
  int time = bwd ? (TT - 1) : 0;
  float ir = cir, iz = ciz, inn = cin;
  if (xp) {
    const float* xr = xp + (size_t)(b * TT + time) * 384 + xofs;
    ir = xr[j]; iz = xr[64 + j]; inn = xr[128 + j];
  }
  for (int t = 0; t < TT; ++t) {
    float irn = cir, izn = ciz, innn = cin;
    if (xp && t < TT - 1) {
      int tn = bwd ? (TT - 2 - t) : (t + 1);
      const float* xn = xp + (size_t)(b * TT + tn) * 384 + xofs;
      irn = xn[j]; izn = xn[64 + j]; innn = xn[128 + j];
    }
    h = gru_step(wr, wz, wn, br, bz, bn, hs[cur], h, ir, iz, inn);
    genout[(size_t)(b * TT + time) * 128 + gid * 64 + j] = h;
    hs[cur ^ 1][j] = h;
    __syncthreads();
    cur ^= 1;
    ir = irn; iz = izn; inn = innn;
    time = bwd ? (time - 1) : (time + 1);
  }
}

// K7: controller forward GRU -> full ys
__global__ __launch_bounds__(64, 1) void ctrl_gru(const float* __restrict__ xp,
    const float* __restrict__ Whh, const float* __restrict__ bhh,
    float* __restrict__ ys) {
  const int b = blockIdx.x;
  const int j = threadIdx.x;
  float wr[64], wz[64], wn[64];
  load_whh(Whh, j, wr, wz, wn);
  const float br = bhh[j], bz = bhh[64 + j], bn = bhh[128 + j];
  __shared__ __align__(16) float hs[2][64];
  float h = 0.f;
  int cur = 0;
  hs[0][j] = h;
  __syncthreads();
  const float* xr = xp + (size_t)(b * TT) * 192;
  float ir = xr[j], iz = xr[64 + j], inn = xr[128 + j];
  for (int t = 0; t < TT; ++t) {
    float irn = 0.f, izn = 0.f, innn = 0.f;
    if (t < TT - 1) {
      const float* xn = xp + (size_t)(b * TT + t + 1) * 192;
      irn = xn[j]; izn = xn[64 + j]; innn = xn[128 + j];
    }
    h = gru_step(wr, wz, wn, br, bz, bn, hs[cur], h, ir, iz, inn);
    ys[(size_t)(b * TT + t) * 64 + j] = h;
    hs[cur ^ 1][j] = h;
    __syncthreads();
    cur ^= 1;
    ir = irn; iz = izn; inn = innn;
  }
}

// K3: g0 linear + reparam + generator h0 projections. One block, 1024 thr.
__global__ __launch_bounds__(1024) void g0_kernel(const float* __restrict__ hTbuf,
    const float* __restrict__ g0lin_W, const float* __restrict__ g0lin_b,
    const float* __restrict__ eps_g0,
    const float* __restrict__ l2gf_W, const float* __restrict__ l2gf_b,
    const float* __restrict__ l2gb_W, const float* __restrict__ l2gb_b,
    float* __restrict__ mu_g0, float* __restrict__ logvar_g0,
    float* __restrict__ h0buf) {
  __shared__ float up[32 * 32];
  __shared__ float g0s[32 * 16];
  const int tid = threadIdx.x;
  const int b = tid >> 5, c = tid & 31;
  float acc = g0lin_b[c];
  for (int k = 0; k < 128; ++k) {
    float hv = (k < 64) ? hTbuf[b * 64 + k] : hTbuf[2048 + b * 64 + (k - 64)];
    acc = fmaf(hv, g0lin_W[c * 128 + k], acc);
  }
  up[b * 32 + c] = acc;
  __syncthreads();
  if (c < 16) {
    float mu = up[b * 32 + c], lv = up[b * 32 + 16 + c];
    mu_g0[b * 16 + c] = mu;
    logvar_g0[b * 16 + c] = lv;
    g0s[b * 16 + c] = mu + eps_g0[b * 16 + c] * __expf(0.5f * lv);
  }
  __syncthreads();
  #pragma unroll
  for (int rep = 0; rep < 4; ++rep) {
    int idx = rep * 1024 + tid;
    int bb = idx >> 7, jj = idx & 127;
    int dir = jj >> 6, j = jj & 63;
    const float* W = dir ? l2gb_W : l2gf_W;
    const float* bias = dir ? l2gb_b : l2gf_b;
    float a = bias[j];
    #pragma unroll
    for (int i = 0; i < 8; ++i) a = fmaf(g0s[bb * 16 + dir * 8 + i], W[j * 8 + i], a);
    h0buf[dir * 2048 + bb * 64 + j] = a;
  }
}

// K5/K11: f = gen_out(.,128) @ fac_W^T(32x128) + fac_b. 4 rows per block.
__global__ __launch_bounds__(128) void f_kernel(const float* __restrict__ gen_out,
    const float* __restrict__ fac_W, const float* __restrict__ fac_b,
    float* __restrict__ f) {
  __shared__ float gl[4 * 130];
  __shared__ float fw[32 * 130];
  const int tid = threadIdx.x;
  const int row0 = blockIdx.x * 4;
  #pragma unroll
  for (int s = 0; s < 4; ++s) {
    int idx = s * 128 + tid;
    gl[(idx >> 7) * 130 + (idx & 127)] = gen_out[(size_t)row0 * 128 + idx];
  }
  for (int s = 0; s < 32; ++s) {
    int idx = s * 128 + tid;
    fw[(idx >> 7) * 130 + (idx & 127)] = fac_W[idx];
  }
  __syncthreads();
  const int r = tid >> 5, c = tid & 31;
  float acc = fac_b[c];
  #pragma unroll 8
  for (int k = 0; k < 128; ++k) acc = fmaf(gl[r * 130 + k], fw[c * 130 + k], acc);
  f[(size_t)(row0 + r) * 32 + c] = acc;
}

// K5b: ctrl_in = [enc_out | f_shift]
__global__ void build_ctrl_in(const float* __restrict__ enc_out,
                              const float* __restrict__ f_init,
                              float* __restrict__ ctrl_in) {
  int idx = blockIdx.x * 256 + threadIdx.x;
  if (idx >= MALL * 160) return;
  int row = idx / 160, i = idx - row * 160;
  float v;
  if (i < 128) v = enc_out[(size_t)row * 128 + i];
  else {
    int t = row & (TT - 1);
    v = (t == 0) ? 0.f : f_init[(size_t)(row - 1) * 32 + (i - 128)];
  }
  ctrl_in[idx] = v;
}

// K8: up = ctrl_ys @ ulin^T + b; split mu/logvar; sample u. 16 rows/block.
__global__ __launch_bounds__(256) void ctrl_out_kernel(const float* __restrict__ ys,
    const float* __restrict__ ulin_W, const float* __restrict__ ulin_b,
    const float* __restrict__ eps_u,
    float* __restrict__ mu_u, float* __restrict__ logvar_u, float* __restrict__ u) {
  __shared__ float ysl[16 * 66];
  __shared__ float wl[16 * 66];
  __shared__ float upl[16 * 16];
  const int tid = threadIdx.x;
  const int row0 = blockIdx.x * 16;
  #pragma unroll
  for (int s = 0; s < 4; ++s) {
    int idx = s * 256 + tid;
    ysl[(idx >> 6) * 66 + (idx & 63)] = ys[(size_t)row0 * 64 + idx];
    wl[(idx >> 6) * 66 + (idx & 63)] = ulin_W[idx];
  }
  __syncthreads();
  const int r = tid >> 4, c = tid & 15;
  float acc = ulin_b[c];
  #pragma unroll 8
  for (int k = 0; k < 64; ++k) acc = fmaf(ysl[r * 66 + k], wl[c * 66 + k], acc);
  upl[r * 16 + c] = acc;
  __syncthreads();
  if (c < 8) {
    int row = row0 + r;
    float mu = upl[r * 16 + c], lv = upl[r * 16 + c + 8];
    mu_u[(size_t)row * 8 + c] = mu;
    logvar_u[(size_t)row * 8 + c] = lv;
    u[(size_t)row * 8 + c] = mu + eps_u[(size_t)row * 8 + c] * __expf(0.5f * lv);
  }
}

// K9: xp_gen2 = u(.,8) @ Wg^T(384x8) + bg. One row per block, 384 threads.
__global__ __launch_bounds__(384) void gen_xp2(const float* __restrict__ u,
    const float* __restrict__ Wg, const float* __restrict__ bg,
    float* __restrict__ xp) {
  __shared__ float us[8];
  const int row = blockIdx.x, o = threadIdx.x;
  if (o < 8) us[o] = u[(size_t)row * 8 + o];
  __syncthreads();
  float4 w0 = *(const float4*)(Wg + o * 8);
  float4 w1 = *(const float4*)(Wg + o * 8 + 4);
  float acc = bg[o];
  acc = fmaf(w0.x, us[0], acc); acc = fmaf(w0.y, us[1], acc);
  acc = fmaf(w0.z, us[2], acc); acc = fmaf(w0.w, us[3], acc);
  acc = fmaf(w1.x, us[4], acc); acc = fmaf(w1.y, us[5], acc);
  acc = fmaf(w1.z, us[6], acc); acc = fmaf(w1.w, us[7], acc);
  xp[(size_t)row * 384 + o] = acc;
}

// K12: logits = f(.,32) @ rate_W^T(4096x32) + rate_b. 16 rows x 256 cols/blk.
__global__ __launch_bounds__(256) void logits_kernel(const float* __restrict__ Fm,
    const float* __restrict__ rate_W, const float* __restrict__ rate_b,
    float* __restrict__ out) {
  __shared__ __align__(16) float fs[16 * 32];
  const int tid = threadIdx.x;
  const int m0 = blockIdx.y * 16;
  const int col = blockIdx.x * 256 + tid;
  ((float2*)fs)[tid] = ((const float2*)(Fm + (size_t)m0 * 32))[tid];
  __syncthreads();
  float w[32];
  #pragma unroll
  for (int k4 = 0; k4 < 8; ++k4) {
    float4 v = *(const float4*)(rate_W + (size_t)col * 32 + k4 * 4);
    w[k4 * 4 + 0] = v.x; w[k4 * 4 + 1] = v.y; w[k4 * 4 + 2] = v.z; w[k4 * 4 + 3] = v.w;
  }
  const float rb = rate_b[col];
  #pragma unroll
  for (int r = 0; r < 16; ++r) {
    float acc = rb;
    #pragma unroll
    for (int k4 = 0; k4 < 8; ++k4) {
      float4 f4 = ((const float4*)fs)[r * 8 + k4];
      acc = fmaf(f4.x, w[k4 * 4 + 0], acc);
      acc = fmaf(f4.y, w[k4 * 4 + 1], acc);
      acc = fmaf(f4.z, w[k4 * 4 + 2], acc);
      acc = fmaf(f4.w, w[k4 * 4 + 3], acc);
    }
    out[(size_t)(m0 + r) * 4096 + col] = acc;
  }
}

// ---------------------------------------------------------------------------
extern "C" void kernel_launch(void* const* d_in, const int* in_sizes, int n_in,
                              void* d_out, int out_size, void* d_ws, size_t ws_size,
                              hipStream_t stream) {
  const float* x        = (const float*)d_in[0];
  const float* eps_g0   = (const float*)d_in[1];
  const float* eps_u    = (const float*)d_in[2];
  const float* g0f_Wih  = (const float*)d_in[3];
  const float* g0f_Whh  = (const float*)d_in[4];
  const float* g0f_bih  = (const float*)d_in[5];
  const float* g0f_bhh  = (const float*)d_in[6];
  const float* g0b_Wih  = (const float*)d_in[7];
  const float* g0b_Whh  = (const float*)d_in[8];
  const float* g0b_bih  = (const float*)d_in[9];
  const float* g0b_bhh  = (const float*)d_in[10];
  const float* cef_Wih  = (const float*)d_in[11];
  const float* cef_Whh  = (const float*)d_in[12];
  const float* cef_bih  = (const float*)d_in[13];
  const float* cef_bhh  = (const float*)d_in[14];
  const float* ceb_Wih  = (const float*)d_in[15];
  const float* ceb_Whh  = (const float*)d_in[16];
  const float* ceb_bih  = (const float*)d_in[17];
  const float* ceb_bhh  = (const float*)d_in[18];
  const float* ctrl_Wih = (const float*)d_in[19];
  const float* ctrl_Whh = (const float*)d_in[20];
  const float* ctrl_bih = (const float*)d_in[21];
  const float* ctrl_bhh = (const float*)d_in[22];
  const float* genf_Wih = (const float*)d_in[23];
  const float* genf_Whh = (const float*)d_in[24];
  const float* genf_bih = (const float*)d_in[25];
  const float* genf_bhh = (const float*)d_in[26];
  const float* genb_Wih = (const float*)d_in[27];
  const float* genb_Whh = (const float*)d_in[28];
  const float* genb_bih = (const float*)d_in[29];
  const float* genb_bhh = (const float*)d_in[30];
  const float* g0lin_W  = (const float*)d_in[31];
  const float* g0lin_b  = (const float*)d_in[32];
  const float* ulin_W   = (const float*)d_in[33];
  const float* ulin_b   = (const float*)d_in[34];
  const float* l2gf_W   = (const float*)d_in[35];
  const float* l2gf_b   = (const float*)d_in[36];
  const float* l2gb_W   = (const float*)d_in[37];
  const float* l2gb_b   = (const float*)d_in[38];
  const float* fac_W    = (const float*)d_in[39];
  const float* fac_b    = (const float*)d_in[40];
  const float* rate_W   = (const float*)d_in[41];
  const float* rate_b   = (const float*)d_in[42];

  float* ws = (float*)d_ws;
  // ws layout (floats); the old Wcat region holds Wh/Wl bf16 pair (same
  // footprint). XP region is overlaid by ctrl_in / xp_ctrl / xp_gen2 after
  // the encoder recurrence consumes XP.
  __bf16* Wh     = (__bf16*)ws;              // 3,145,728 bf16 (=1.57M floats)
  __bf16* Wl     = Wh + 3145728;             // 3,145,728 bf16
  float* XP      = ws + 3145728;             // 12,582,912
  float* ctrl_in = XP;                       // 2,621,440 (overlay)
  float* xp_ctrl = XP + 2621440;             // 3,145,728 (overlay)
  float* xp_gen2 = XP + 5767168;             // 6,291,456 (overlay)
  float* bcat    = XP + 12582912;            // 768
  float* Wg      = bcat + 768;               // 3,072
  float* bg      = Wg + 3072;                // 384
  float* hTbuf   = bg + 384;                 // 4,096
  float* h0buf   = hTbuf + 4096;             // 4,096
  float* enc_out = h0buf + 4096;             // 2,097,152
  float* genout  = enc_out + 2097152;        // 2,097,152
  float* f_init  = genout + 2097152;         // 524,288
  float* ctrl_ys = f_init + 524288;          // 1,048,576
  float* u_buf   = ctrl_ys + 1048576;        // 131,072

  float* out  = (float*)d_out;
  float* f_t  = out + OFS_FT;
  // Xh/Xl scratch lives in the logits region of d_out (dead until K12):
  // 67,108,864 bf16 each = exactly the 67,108,864-float logits block.
  __bf16* Xh = (__bf16*)out;
  __bf16* Xl = Xh + 67108864;

  // K-1: split-convert x -> Xh/Xl
  cvt_split<<<32768, 256, 0, stream>>>(x, Xh, Xl);
  // K0: pack concatenated weights (Wih -> bf16 hi/lo pair)
  pack_kernel<<<12305, 256, 0, stream>>>(g0f_Wih, g0b_Wih, cef_Wih, ceb_Wih,
                                         g0f_bih, g0b_bih, cef_bih, ceb_bih,
                                         genf_Wih, genb_Wih, genf_bih, genb_bih,
                                         Wh, Wl, bcat, Wg, bg);
  // K1: big fused encoder input projection via 3-term split bf16 MFMA
  gemm_bf16split<<<dim3(6, 128), 256, 0, stream>>>(Xh, Xl, Wh, Wl, bcat, XP);
  // K2: 4 encoder GRU recurrences
  enc_gru<<<128, 64, 0, stream>>>(XP, g0f_Whh, g0b_Whh, cef_Whh, ceb_Whh,
                                  g0f_bhh, g0b_bhh, cef_bhh, ceb_bhh,
                                  hTbuf, enc_out);
  // K3: g0 linear + reparam + generator h0
  g0_kernel<<<1, 1024, 0, stream>>>(hTbuf, g0lin_W, g0lin_b, eps_g0,
                                    l2gf_W, l2gf_b, l2gb_W, l2gb_b,
                                    out + OFS_MUG0, out + OFS_LVG0, h0buf);
  // K4: generator pass 1 (u = 0 -> input proj = bih only)
  gen_gru<<<64, 64, 0, stream>>>(nullptr, bg, genf_Whh, genb_Whh,
                                 genf_bhh, genb_bhh, h0buf, genout);
  // K5: f_init
  f_kernel<<<4096, 128, 0, stream>>>(genout, fac_W, fac_b, f_init);
  // K5b: controller input concat
  build_ctrl_in<<<10240, 256, 0, stream>>>(enc_out, f_init, ctrl_in);
  // K6: controller input projection (16384x192, K=160) fp32
  sgemm_nt<<<dim3(3, 256), 256, 0, stream>>>(ctrl_in, ctrl_Wih, ctrl_bih, xp_ctrl,
                                             MALL, 192, 160, 160, 160, 192);
  // K7: controller GRU
  ctrl_gru<<<32, 64, 0, stream>>>(xp_ctrl, ctrl_Whh, ctrl_bhh, ctrl_ys);
  // K8: u-posterior linear + reparam
  ctrl_out_kernel<<<1024, 256, 0, stream>>>(ctrl_ys, ulin_W, ulin_b, eps_u,
                                            out + OFS_MUU, out + OFS_LVU, u_buf);
  // K9: generator pass-2 input projection
  gen_xp2<<<16384, 384, 0, stream>>>(u_buf, Wg, bg, xp_gen2);
  // K10: generator pass 2
  gen_gru<<<64, 64, 0, stream>>>(xp_gen2, bg, genf_Whh, genb_Whh,
                                 genf_bhh, genb_bhh, h0buf, genout);
  // K11: f_t (written straight to d_out; also read by K12)
  f_kernel<<<4096, 128, 0, stream>>>(genout, fac_W, fac_b, f_t);
  // K12: logits (overwrites the Xh/Xl scratch region — Xh/Xl dead since K1)
  logits_kernel<<<dim3(16, 1024), 256, 0, stream>>>(f_t, rate_W, rate_b, out);
}